// Round 10
// baseline (249.698 us; speedup 1.0000x reference)
//
#include <hip/hip_runtime.h>

#define NB 256
#define NT 512
#define NI 64
#define NH 256
#define NO 16

typedef __attribute__((ext_vector_type(8))) short short8;
typedef __attribute__((ext_vector_type(8))) __bf16 bf16x8;
typedef __attribute__((ext_vector_type(4))) float f32x4;
typedef __attribute__((ext_vector_type(4))) int int4v;
typedef __attribute__((ext_vector_type(8))) int int8v;

__device__ __forceinline__ unsigned short f2bf(float f) {
  unsigned u = __builtin_bit_cast(unsigned, f);
  u += 0x7fffu + ((u >> 16) & 1u);          // round-to-nearest-even
  return (unsigned short)(u >> 16);
}

__device__ __forceinline__ f32x4 mfma16(short8 a, short8 b, f32x4 c) {
  return __builtin_amdgcn_mfma_f32_16x16x32_bf16(
      __builtin_bit_cast(bf16x8, a), __builtin_bit_cast(bf16x8, b), c, 0, 0, 0);
}

// fp8(e4m3) K=128 MFMA via f8f6f4, block scales pinned to 1.0.
__device__ __forceinline__ f32x4 mfma_fp8(int8v a, int8v b, f32x4 c) {
  return __builtin_amdgcn_mfma_scale_f32_16x16x128_f8f6f4(
      a, b, c, 0, 0, 0, 0x7f7f7f7f, 0, 0x7f7f7f7f);
}

__device__ __forceinline__ short8 pack8v(f32x4 lo, f32x4 hi) {
  short8 r;
#pragma unroll
  for (int i = 0; i < 4; ++i) {
    r[i]     = (short)f2bf(lo[i]);
    r[i + 4] = (short)f2bf(hi[i]);
  }
  return r;
}

__device__ __forceinline__ short8 pack8(const float* __restrict__ p) {
  return pack8v(*reinterpret_cast<const f32x4*>(p),
                *reinterpret_cast<const f32x4*>(p + 4));
}

// LDS-only barrier: drain DS ops, sync; global stores/loads stay in flight.
__device__ __forceinline__ void step_barrier() {
  asm volatile("s_waitcnt lgkmcnt(0)" ::: "memory");
  __builtin_amdgcn_s_barrier();
  asm volatile("" ::: "memory");
}

// One block per batch. 1024 threads = 16 waves (4/SIMD — latency hiding).
// Wave w owns hidden units j in [w*16, w*16+16); lane col ll <-> j = w*16+ll.
// h2h via fp8 K=128 MFMA: A = broadcast h (e4m3 linear byte buffer), B =
// per-row-scaled Wh (e4m3); 2 INDEPENDENT MFMAs/wave/step (kc=0,1).
// xi for each 16-step window lives in REGISTERS (LDS [j][t] transpose).
__global__ __launch_bounds__(1024, 4)
void rnn_fused(const float* __restrict__ x,  const float* __restrict__ Wi,
               const float* __restrict__ bi, const float* __restrict__ Wh,
               const float* __restrict__ bh, const float* __restrict__ Wo,
               const float* __restrict__ bo, const float* __restrict__ h0,
               float* __restrict__ dout)
{
  const int b   = blockIdx.x;
  const int tid = threadIdx.x;
  const int w   = tid >> 6;   // wave 0..15
  const int l   = tid & 63;   // lane
  const int lg  = l >> 4;     // 16-lane group (k-chunk)
  const int ll  = l & 15;     // col within tile

  __shared__ __align__(16) unsigned char  hq8[2][256];       // e4m3 h, linear j
  __shared__ __align__(16) unsigned short rnnwin[16 * NH];   // 8 KB bf16 ring
  __shared__ __align__(16) float          xi_lds[NH * 20];   // [j][t(16)+pad4]

  float* outp = dout;                              // [B,T,O]
  float* hidp = dout + (size_t)NB * NT * NO;       // [B,H]
  float* rnnp = hidp + (size_t)NB * NH;            // [B,T,H]

  const f32x4 cz = {0.f, 0.f, 0.f, 0.f};

  const int j   = w * 16 + ll;     // this lane's hidden unit
  const int j20 = j * 20;

  // ---- Wh -> e4m3 B-fragments, per-row scale 224/m; col n=ll -> row j,
  //      k = kc*128 + lg*32 + e ----
  int8v wq8[2];
  float dq;
  {
    const float* wr = Wh + (size_t)j * NH;
    float m = 0.f;
#pragma unroll
    for (int kc = 0; kc < 2; ++kc)
#pragma unroll
      for (int q8 = 0; q8 < 8; ++q8) {
        f32x4 v = *reinterpret_cast<const f32x4*>(wr + kc * 128 + lg * 32 + q8 * 4);
#pragma unroll
        for (int i = 0; i < 4; ++i) m = fmaxf(m, fabsf(v[i]));
      }
    m = fmaxf(m, __shfl_xor(m, 16));
    m = fmaxf(m, __shfl_xor(m, 32));
    const float s = (m > 0.f) ? 224.f / m : 0.f;
    dq = m * (1.f / 224.f);
#pragma unroll
    for (int kc = 0; kc < 2; ++kc) {
      int8v t8;
#pragma unroll
      for (int q8 = 0; q8 < 8; ++q8) {
        f32x4 v = *reinterpret_cast<const f32x4*>(wr + kc * 128 + lg * 32 + q8 * 4);
        int lo = __builtin_amdgcn_cvt_pk_fp8_f32(v[0] * s, v[1] * s, 0, false);
        t8[q8] = __builtin_amdgcn_cvt_pk_fp8_f32(v[2] * s, v[3] * s, lo, true);
      }
      wq8[kc] = t8;
    }
  }

  // ---- bf16 i2h weights (8 VGPR): B-frag col ll -> row j, k = kx*32+lg*8+e
  short8 wif[2];
#pragma unroll
  for (int kx = 0; kx < 2; ++kx)
    wif[kx] = pack8(Wi + (size_t)j * NI + kx * 32 + lg * 8);

  const float breg = bi[j] + bh[j];
  const float bout = bo[ll];
  float h_reg = h0[j];

  // ---- init hq8[0] from h0 ----
  if (tid < 128) {
    int v = __builtin_amdgcn_cvt_pk_fp8_f32(h0[2 * tid], h0[2 * tid + 1], 0, false);
    *(unsigned short*)&hq8[0][2 * tid] = (unsigned short)v;
  }

  // ---- x prefetch (one window ahead): lane row ll, 16 f32 ----
  const float* xrow = x + (size_t)b * NT * NI + (size_t)ll * NI + lg * 8;
  f32x4 xpre[4];
  xpre[0] = *reinterpret_cast<const f32x4*>(xrow);
  xpre[1] = *reinterpret_cast<const f32x4*>(xrow + 4);
  xpre[2] = *reinterpret_cast<const f32x4*>(xrow + 32);
  xpre[3] = *reinterpret_cast<const f32x4*>(xrow + 36);

  __syncthreads();

  auto outproj = [&](int tbase) {    // out[tbase-16 .. tbase-1] from rnnwin
    f32x4 oacc = cz;
#pragma unroll
    for (int kt = 0; kt < 8; ++kt) {
      short8 wo = pack8(Wo + (size_t)ll * NH + kt * 32 + lg * 8);
      const char* ap = (const char*)rnnwin + ll * 512 +
                       ((kt * 64 + lg * 16) ^ (ll << 4));
      short8 af = *reinterpret_cast<const short8*>(ap);
      oacc = mfma16(af, wo, oacc);
    }
#pragma unroll
    for (int r = 0; r < 4; ++r) {
      const int tp = lg * 4 + r;
      outp[((size_t)b * NT + tbase - 16 + tp) * NO + ll] = oacc[r] + bout;
    }
  };

#define STEP(TT, XIV)                                                          \
  {                                                                            \
    const int t    = (TT);                                                     \
    const int trow = t & 15;                                                   \
    const int p    = t & 1;                                                    \
    const unsigned char* hb = hq8[p];                                          \
    int8v A0, A1;                                                              \
    *(int4v*)&A0       = *(const int4v*)(hb + lg * 32);                        \
    *((int4v*)&A0 + 1) = *(const int4v*)(hb + lg * 32 + 16);                   \
    *(int4v*)&A1       = *(const int4v*)(hb + 128 + lg * 32);                  \
    *((int4v*)&A1 + 1) = *(const int4v*)(hb + 128 + lg * 32 + 16);             \
    const float hx = h_reg + (XIV);    /* xi already has bias */               \
    f32x4 acc0 = mfma_fp8(A0, wq8[0], cz);                                     \
    f32x4 acc1 = mfma_fp8(A1, wq8[1], cz);                                     \
    const float a = fminf(fmaxf(fmaf(acc0[0] + acc1[0], dq, hx), 0.f), 1.f);   \
    h_reg = a;                                                                 \
    if (lg == 0) {                                                             \
      int hv = __builtin_amdgcn_cvt_pk_fp8_f32(a, a, 0, false);                \
      hq8[p ^ 1][j] = (unsigned char)hv;                                       \
      unsigned bfp;                                                            \
      asm("v_cvt_pk_bf16_f32 %0, %1, %2" : "=v"(bfp) : "v"(a), "v"(a));        \
      *(unsigned short*)((char*)rnnwin + trow * 512 +                          \
                         ((2 * j) ^ (trow << 4))) = (unsigned short)bfp;       \
      rnnp[((size_t)b * NT + t) * NH + j] = a;                                 \
    }                                                                          \
    step_barrier();                                                            \
  }

#pragma unroll 1
  for (int t0 = 0; t0 < NT; t0 += 16) {
    // ---- window boundary ----
    if (t0 > 0 && w == (((t0 >> 4) - 1) & 15)) outproj(t0);   // rotating wave
    {
      short8 xf0 = pack8v(xpre[0], xpre[1]);
      short8 xf1 = pack8v(xpre[2], xpre[3]);
      f32x4 acc = mfma16(xf0, wif[0], cz);
      acc = mfma16(xf1, wif[1], acc);
      f32x4 xo;
#pragma unroll
      for (int r = 0; r < 4; ++r) xo[r] = acc[r] + breg;   // bias folded
      *(f32x4*)&xi_lds[j20 + lg * 4] = xo;                 // [j][t] transpose
    }
    if (t0 + 16 < NT) {
      const float* xp = x + (size_t)b * NT * NI + (size_t)(t0 + 16 + ll) * NI + lg * 8;
      xpre[0] = *reinterpret_cast<const f32x4*>(xp);
      xpre[1] = *reinterpret_cast<const f32x4*>(xp + 4);
      xpre[2] = *reinterpret_cast<const f32x4*>(xp + 32);
      xpre[3] = *reinterpret_cast<const f32x4*>(xp + 36);
    }
    step_barrier();

    // ---- whole window's xi into registers (statically indexed below) ----
    f32x4 xq0 = *(const f32x4*)&xi_lds[j20];
    f32x4 xq1 = *(const f32x4*)&xi_lds[j20 + 4];
    f32x4 xq2 = *(const f32x4*)&xi_lds[j20 + 8];
    f32x4 xq3 = *(const f32x4*)&xi_lds[j20 + 12];

    STEP(t0 + 0,  xq0[0]) STEP(t0 + 1,  xq0[1])
    STEP(t0 + 2,  xq0[2]) STEP(t0 + 3,  xq0[3])
    STEP(t0 + 4,  xq1[0]) STEP(t0 + 5,  xq1[1])
    STEP(t0 + 6,  xq1[2]) STEP(t0 + 7,  xq1[3])
    STEP(t0 + 8,  xq2[0]) STEP(t0 + 9,  xq2[1])
    STEP(t0 + 10, xq2[2]) STEP(t0 + 11, xq2[3])
    STEP(t0 + 12, xq3[0]) STEP(t0 + 13, xq3[1])
    STEP(t0 + 14, xq3[2]) STEP(t0 + 15, xq3[3])
  }
#undef STEP

  // ---- epilogue: final window out-proj + hidden ----
  if (w == 15) outproj(NT);
  if (lg == 0) hidp[(size_t)b * NH + j] = h_reg;
}

extern "C" void kernel_launch(void* const* d_in, const int* in_sizes, int n_in,
                              void* d_out, int out_size, void* d_ws, size_t ws_size,
                              hipStream_t stream) {
  const float* x  = (const float*)d_in[0];
  const float* Wi = (const float*)d_in[1];
  const float* bi = (const float*)d_in[2];
  const float* Wh = (const float*)d_in[3];
  const float* bh = (const float*)d_in[4];
  const float* Wo = (const float*)d_in[5];
  const float* bo = (const float*)d_in[6];
  const float* h0 = (const float*)d_in[7];
  rnn_fused<<<dim3(NB), dim3(1024), 0, stream>>>(x, Wi, bi, Wh, bh, Wo, bo, h0,
                                                 (float*)d_out);
}

// Round 11
// 192.553 us; speedup vs baseline: 1.2968x; 1.2968x over previous
//
#include <hip/hip_runtime.h>

#define NB 256
#define NT 512
#define NI 64
#define NH 256
#define NO 16

typedef __attribute__((ext_vector_type(8))) short short8;
typedef __attribute__((ext_vector_type(8))) __bf16 bf16x8;
typedef __attribute__((ext_vector_type(2))) float f32x2;
typedef __attribute__((ext_vector_type(4))) float f32x4;
typedef __attribute__((ext_vector_type(4))) int int4v;
typedef __attribute__((ext_vector_type(8))) int int8v;

__device__ __forceinline__ unsigned short f2bf(float f) {
  unsigned u = __builtin_bit_cast(unsigned, f);
  u += 0x7fffu + ((u >> 16) & 1u);          // round-to-nearest-even
  return (unsigned short)(u >> 16);
}

__device__ __forceinline__ f32x4 mfma16(short8 a, short8 b, f32x4 c) {
  return __builtin_amdgcn_mfma_f32_16x16x32_bf16(
      __builtin_bit_cast(bf16x8, a), __builtin_bit_cast(bf16x8, b), c, 0, 0, 0);
}

// fp8(e4m3) K=128 MFMA via f8f6f4, block scales pinned to 1.0.
__device__ __forceinline__ f32x4 mfma_fp8(int8v a, int8v b, f32x4 c) {
  return __builtin_amdgcn_mfma_scale_f32_16x16x128_f8f6f4(
      a, b, c, 0, 0, 0, 0x7f7f7f7f, 0, 0x7f7f7f7f);
}

__device__ __forceinline__ short8 pack8v(f32x4 lo, f32x4 hi) {
  short8 r;
#pragma unroll
  for (int i = 0; i < 4; ++i) {
    r[i]     = (short)f2bf(lo[i]);
    r[i + 4] = (short)f2bf(hi[i]);
  }
  return r;
}

__device__ __forceinline__ short8 pack8(const float* __restrict__ p) {
  return pack8v(*reinterpret_cast<const f32x4*>(p),
                *reinterpret_cast<const f32x4*>(p + 4));
}

// LDS-only barrier: drain DS ops, sync; global stores/loads stay in flight.
__device__ __forceinline__ void step_barrier() {
  asm volatile("s_waitcnt lgkmcnt(0)" ::: "memory");
  __builtin_amdgcn_s_barrier();
  asm volatile("" ::: "memory");
}

// One block per batch. 512 threads = 8 waves (2/SIMD).
// h2h via fp8 K=128 MFMA: A = broadcast h (e4m3 linear 256B buffer), B =
// per-row-scaled Wh (e4m3); 4 INDEPENDENT depth-1 MFMAs per wave per step.
// Even/odd j-map: lane ll owns j = w*32+2*ll (+1) -> packed local writes.
// xi for each 16-step window lives in REGISTERS (bias folded at the
// [j][t]-transpose write); no per-step xi LDS read.
__global__ __launch_bounds__(512, 2)
void rnn_fused(const float* __restrict__ x,  const float* __restrict__ Wi,
               const float* __restrict__ bi, const float* __restrict__ Wh,
               const float* __restrict__ bh, const float* __restrict__ Wo,
               const float* __restrict__ bo, const float* __restrict__ h0,
               float* __restrict__ dout)
{
  const int b   = blockIdx.x;
  const int tid = threadIdx.x;
  const int w   = tid >> 6;   // wave 0..7
  const int l   = tid & 63;   // lane
  const int lg  = l >> 4;     // 16-lane group
  const int ll  = l & 15;     // index within tile

  __shared__ __align__(16) unsigned char  hq8[2][256];      // e4m3 h, linear j
  __shared__ __align__(16) unsigned short rnnwin[16 * NH];  // 8 KB bf16 ring
  __shared__ __align__(16) float          xi_t[NH * 20];    // [j][t(16)+pad4]

  float* outp = dout;                              // [B,T,O]
  float* hidp = dout + (size_t)NB * NT * NO;       // [B,H]
  float* rnnp = hidp + (size_t)NB * NH;            // [B,T,H]

  const f32x4 cz = {0.f, 0.f, 0.f, 0.f};

  // ---- Wh -> e4m3 B-fragments, per-row scale 224/m; row j = w*32+2*ll+jt,
  //      k = kc*128 + lg*32 + e ----
  int8v wq8[2][2];
  float dq[2];
#pragma unroll
  for (int jt = 0; jt < 2; ++jt) {
    const int j = w * 32 + 2 * ll + jt;
    const float* wr = Wh + (size_t)j * NH;
    float m = 0.f;
#pragma unroll
    for (int kc = 0; kc < 2; ++kc)
#pragma unroll
      for (int q8 = 0; q8 < 8; ++q8) {
        f32x4 v = *reinterpret_cast<const f32x4*>(wr + kc * 128 + lg * 32 + q8 * 4);
#pragma unroll
        for (int i = 0; i < 4; ++i) m = fmaxf(m, fabsf(v[i]));
      }
    m = fmaxf(m, __shfl_xor(m, 16));
    m = fmaxf(m, __shfl_xor(m, 32));
    const float s = (m > 0.f) ? 224.f / m : 0.f;
    dq[jt] = m * (1.f / 224.f);
#pragma unroll
    for (int kc = 0; kc < 2; ++kc) {
      int8v t8;
#pragma unroll
      for (int q8 = 0; q8 < 8; ++q8) {
        f32x4 v = *reinterpret_cast<const f32x4*>(wr + kc * 128 + lg * 32 + q8 * 4);
        int lo = __builtin_amdgcn_cvt_pk_fp8_f32(v[0] * s, v[1] * s, 0, false);
        t8[q8] = __builtin_amdgcn_cvt_pk_fp8_f32(v[2] * s, v[3] * s, lo, true);
      }
      wq8[jt][kc] = t8;
    }
  }

  // ---- bf16 i2h weights (16 VGPR); out-proj loaded per window ----
  short8 wif[2][2];
  float bregW[2];
#pragma unroll
  for (int jt = 0; jt < 2; ++jt) {
    const int j = w * 32 + jt * 16 + ll;
#pragma unroll
    for (int kx = 0; kx < 2; ++kx)
      wif[jt][kx] = pack8(Wi + (size_t)j * NI + kx * 32 + lg * 8);
    bregW[jt] = bi[j] + bh[j];          // bias folded at xi write (write map!)
  }

  const int je = w * 32 + 2 * ll;      // even j this lane owns (+1 = odd)
  const float bout = bo[ll];

  float h_reg0 = h0[je];
  float h_reg1 = h0[je + 1];

  // ---- init hq8[0] from h0 ----
  if (tid < 128) {
    int v = __builtin_amdgcn_cvt_pk_fp8_f32(h0[2 * tid], h0[2 * tid + 1], 0, false);
    *(unsigned short*)&hq8[0][2 * tid] = (unsigned short)v;
  }

  // ---- x prefetch (one window ahead): lane row ll, 16 f32 ----
  const float* xrow = x + (size_t)b * NT * NI + (size_t)ll * NI + lg * 8;
  f32x4 xpre[4];
  xpre[0] = *reinterpret_cast<const f32x4*>(xrow);
  xpre[1] = *reinterpret_cast<const f32x4*>(xrow + 4);
  xpre[2] = *reinterpret_cast<const f32x4*>(xrow + 32);
  xpre[3] = *reinterpret_cast<const f32x4*>(xrow + 36);

  __syncthreads();

  auto outproj = [&](int tbase) {    // out[tbase-16 .. tbase-1] from rnnwin
    f32x4 oacc = cz;
#pragma unroll
    for (int kt = 0; kt < 8; ++kt) {
      short8 wo = pack8(Wo + (size_t)ll * NH + kt * 32 + lg * 8);
      const char* ap = (const char*)rnnwin + ll * 512 +
                       ((kt * 64 + lg * 16) ^ (ll << 4));
      short8 af = *reinterpret_cast<const short8*>(ap);
      oacc = mfma16(af, wo, oacc);
    }
#pragma unroll
    for (int r = 0; r < 4; ++r) {
      const int tp = lg * 4 + r;
      outp[((size_t)b * NT + tbase - 16 + tp) * NO + ll] = oacc[r] + bout;
    }
  };

#define STEP(TT, XIV0, XIV1)                                                   \
  {                                                                            \
    const int t    = (TT);                                                     \
    const int trow = t & 15;                                                   \
    const int p    = t & 1;                                                    \
    const unsigned char* hb = hq8[p];                                          \
    int8v A0, A1;                                                              \
    *(int4v*)&A0       = *(const int4v*)(hb + lg * 32);                        \
    *((int4v*)&A0 + 1) = *(const int4v*)(hb + lg * 32 + 16);                   \
    *(int4v*)&A1       = *(const int4v*)(hb + 128 + lg * 32);                  \
    *((int4v*)&A1 + 1) = *(const int4v*)(hb + 128 + lg * 32 + 16);             \
    const float hx0 = h_reg0 + (XIV0);   /* xi carries bias */                 \
    const float hx1 = h_reg1 + (XIV1);                                         \
    f32x4 a00 = mfma_fp8(A0, wq8[0][0], cz);                                   \
    f32x4 a10 = mfma_fp8(A0, wq8[1][0], cz);                                   \
    f32x4 a01 = mfma_fp8(A1, wq8[0][1], cz);                                   \
    f32x4 a11 = mfma_fp8(A1, wq8[1][1], cz);                                   \
    const float s0 = a00[0] + a01[0];                                          \
    const float s1 = a10[0] + a11[0];                                          \
    const float a0 = __builtin_amdgcn_fmed3f(fmaf(s0, dq[0], hx0), 0.f, 1.f);  \
    const float a1 = __builtin_amdgcn_fmed3f(fmaf(s1, dq[1], hx1), 0.f, 1.f);  \
    h_reg0 = a0; h_reg1 = a1;                                                  \
    if (lg == 0) {                                                             \
      int hv = __builtin_amdgcn_cvt_pk_fp8_f32(a0, a1, 0, false);              \
      *(unsigned short*)&hq8[p ^ 1][je] = (unsigned short)hv;                  \
      *(unsigned*)((char*)rnnwin + trow * 512 +                                \
                   ((4 * (w * 16 + ll)) ^ (trow << 4))) =                      \
          (unsigned)f2bf(a0) | ((unsigned)f2bf(a1) << 16);                     \
      f32x2 o2; o2[0] = a0; o2[1] = a1;                                        \
      *(f32x2*)(rnnp + ((size_t)b * NT + t) * NH + je) = o2;                   \
    }                                                                          \
    step_barrier();                                                            \
  }

#pragma unroll 1
  for (int t0 = 0; t0 < NT; t0 += 16) {
    // ---- window boundary: rotating out-proj + i2h GEMM + x prefetch ----
    if (t0 > 0 && w == (((t0 >> 4) - 1) & 7)) outproj(t0);
    {
      short8 xf0 = pack8v(xpre[0], xpre[1]);
      short8 xf1 = pack8v(xpre[2], xpre[3]);
#pragma unroll
      for (int jt = 0; jt < 2; ++jt) {
        f32x4 acc = mfma16(xf0, wif[jt][0], cz);
        acc = mfma16(xf1, wif[jt][1], acc);
        const int j = w * 32 + jt * 16 + ll;
        f32x4 xo;
#pragma unroll
        for (int r = 0; r < 4; ++r) xo[r] = acc[r] + bregW[jt];
        *(f32x4*)&xi_t[j * 20 + lg * 4] = xo;   // [j][t] transpose, bias in
      }
    }
    if (t0 + 16 < NT) {
      const float* xp = x + (size_t)b * NT * NI + (size_t)(t0 + 16 + ll) * NI + lg * 8;
      xpre[0] = *reinterpret_cast<const f32x4*>(xp);
      xpre[1] = *reinterpret_cast<const f32x4*>(xp + 4);
      xpre[2] = *reinterpret_cast<const f32x4*>(xp + 32);
      xpre[3] = *reinterpret_cast<const f32x4*>(xp + 36);
    }
    step_barrier();

    // ---- whole window's xi into registers (statically indexed below) ----
    f32x4 xqe[4], xqo[4];
#pragma unroll
    for (int q = 0; q < 4; ++q) {
      xqe[q] = *(const f32x4*)&xi_t[je * 20 + q * 4];
      xqo[q] = *(const f32x4*)&xi_t[(je + 1) * 20 + q * 4];
    }

    STEP(t0 + 0,  xqe[0][0], xqo[0][0]) STEP(t0 + 1,  xqe[0][1], xqo[0][1])
    STEP(t0 + 2,  xqe[0][2], xqo[0][2]) STEP(t0 + 3,  xqe[0][3], xqo[0][3])
    STEP(t0 + 4,  xqe[1][0], xqo[1][0]) STEP(t0 + 5,  xqe[1][1], xqo[1][1])
    STEP(t0 + 6,  xqe[1][2], xqo[1][2]) STEP(t0 + 7,  xqe[1][3], xqo[1][3])
    STEP(t0 + 8,  xqe[2][0], xqo[2][0]) STEP(t0 + 9,  xqe[2][1], xqo[2][1])
    STEP(t0 + 10, xqe[2][2], xqo[2][2]) STEP(t0 + 11, xqe[2][3], xqo[2][3])
    STEP(t0 + 12, xqe[3][0], xqo[3][0]) STEP(t0 + 13, xqe[3][1], xqo[3][1])
    STEP(t0 + 14, xqe[3][2], xqo[3][2]) STEP(t0 + 15, xqe[3][3], xqo[3][3])
  }
#undef STEP

  // ---- epilogue: final window out-proj (rotation slot 31&7 = 7) + hidden ----
  if (w == 7) outproj(NT);
  if (lg == 0) {
    f32x2 h2; h2[0] = h_reg0; h2[1] = h_reg1;
    *(f32x2*)(hidp + (size_t)b * NH + je) = h2;
  }
}

extern "C" void kernel_launch(void* const* d_in, const int* in_sizes, int n_in,
                              void* d_out, int out_size, void* d_ws, size_t ws_size,
                              hipStream_t stream) {
  const float* x  = (const float*)d_in[0];
  const float* Wi = (const float*)d_in[1];
  const float* bi = (const float*)d_in[2];
  const float* Wh = (const float*)d_in[3];
  const float* bh = (const float*)d_in[4];
  const float* Wo = (const float*)d_in[5];
  const float* bo = (const float*)d_in[6];
  const float* h0 = (const float*)d_in[7];
  rnn_fused<<<dim3(NB), dim3(512), 0, stream>>>(x, Wi, bi, Wh, bh, Wo, bo, h0,
                                                (float*)d_out);
}